// Round 3
// baseline (6214.289 us; speedup 1.0000x reference)
//
#include <hip/hip_runtime.h>

typedef unsigned int u32;
typedef unsigned short u16;
typedef _Float16 f16;
typedef f16 f16x2 __attribute__((ext_vector_type(2)));

__device__ __forceinline__ float fdot2(u32 a, u32 b, float c) {
#if __has_builtin(__builtin_amdgcn_fdot2)
    return __builtin_amdgcn_fdot2(__builtin_bit_cast(f16x2, a),
                                  __builtin_bit_cast(f16x2, b), c, false);
#else
    f16x2 av = __builtin_bit_cast(f16x2, a), bv = __builtin_bit_cast(f16x2, b);
    c += (float)av[0] * (float)bv[0];
    c += (float)av[1] * (float)bv[1];
    return c;
#endif
}

__device__ __forceinline__ u32 pack2h(float a, float b) {
    f16x2 h; h[0] = (f16)a; h[1] = (f16)b;
    return __builtin_bit_cast(u32, h);
}
__device__ __forceinline__ float h2f(u16 x) { return (float)__builtin_bit_cast(f16, x); }
__device__ __forceinline__ u16 f2h(float x) { f16 h = (f16)x; return __builtin_bit_cast(u16, h); }

__device__ __forceinline__ float fexp(float x) {
#if __has_builtin(__builtin_amdgcn_exp2f)
    return __builtin_amdgcn_exp2f(x * 1.44269504088896f);
#else
    return __expf(x);
#endif
}
__device__ __forceinline__ float frcp(float x) {
#if __has_builtin(__builtin_amdgcn_rcpf)
    return __builtin_amdgcn_rcpf(x);
#else
    return 1.0f / x;
#endif
}
__device__ __forceinline__ float fsigmoid(float x) { return frcp(1.0f + fexp(-x)); }
__device__ __forceinline__ float ftanh_pos(float x) { return 1.0f - 2.0f * frcp(fexp(2.0f * x) + 1.0f); }

template <int CTRL>
__device__ __forceinline__ float dpp_xor_add(float x) {
    int y = __builtin_amdgcn_update_dpp(0, __builtin_bit_cast(int, x), CTRL, 0xF, 0xF, true);
    return x + __builtin_bit_cast(float, y);
}

// ---------------------------------------------------------------------------
// K0: pack weights to f16 pairs.
//   WpkT[d][p] = (Wi[d][2p], Wi[d][2p+1])   d<512, p<256   (row-major rows)
//   Wypk[p][d] = (Wy[d][2p], Wy[d][2p+1])   (K2 epilogue layout)
// ---------------------------------------------------------------------------
__global__ __launch_bounds__(256) void k0_pack(const float* __restrict__ Wi,
                                               const float* __restrict__ Wy,
                                               u32* __restrict__ WpkT,
                                               u32* __restrict__ Wypk) {
    const int bx = blockIdx.x, tid = threadIdx.x;
    if (bx < 512) {
        const float2 v = *(const float2*)(Wi + (size_t)bx * 512 + 2 * tid);
        WpkT[(size_t)bx * 256 + tid] = pack2h(v.x, v.y);
    } else {
        const int p = bx - 512;  // 0..255
        #pragma unroll
        for (int r = 0; r < 2; ++r) {
            const int d = tid + 256 * r;
            Wypk[(size_t)p * 512 + d] =
                pack2h(Wy[(size_t)d * 512 + 2 * p], Wy[(size_t)d * 512 + 2 * p + 1]);
        }
    }
}

// ---------------------------------------------------------------------------
// K1: gate pre-activations (parallel over all t). Unchanged from round 2.
// ---------------------------------------------------------------------------
__global__ __launch_bounds__(256) void k1_gates(
    const float* __restrict__ word,
    const float* __restrict__ Wi, const float* __restrict__ Wz, const float* __restrict__ Wo,
    const float* __restrict__ bi, const float* __restrict__ bz, const float* __restrict__ bo,
    u16* __restrict__ Xi, u16* __restrict__ Xz, u16* __restrict__ Xo)
{
    __shared__ u32 ws2[3][16][132];
    __shared__ u32 xs2[2][16][36];

    const int tid = threadIdx.x;
    const int d_l = tid & 63;
    const int bq  = tid >> 6;
    const int t0  = blockIdx.x * 2;
    const int d0  = blockIdx.y * 128;

    const float* Wg[3] = {Wi, Wz, Wo};

    float acc[2][2][8][3];
    #pragma unroll
    for (int tt = 0; tt < 2; ++tt)
        #pragma unroll
        for (int db = 0; db < 2; ++db)
            #pragma unroll
            for (int j = 0; j < 8; ++j)
                #pragma unroll
                for (int g = 0; g < 3; ++g) acc[tt][db][j][g] = 0.0f;

    for (int k0 = 0; k0 < 512; k0 += 32) {
        {
            const int p = tid & 15, bg = tid >> 4;
            #pragma unroll
            for (int tt = 0; tt < 2; ++tt)
                #pragma unroll
                for (int j = 0; j < 2; ++j) {
                    const int bb = bg * 2 + j;
                    const float2 v = *(const float2*)(word + (((size_t)(t0 + tt) * 32 + bb) * 512 + k0 + 2 * p));
                    xs2[tt][p][bb] = pack2h(v.x, v.y);
                }
        }
        {
            const int q = tid & 7, r = tid >> 3;
            #pragma unroll
            for (int g = 0; g < 3; ++g)
                #pragma unroll
                for (int s = 0; s < 4; ++s) {
                    const int i = r + 32 * s;
                    const float4 v = *(const float4*)(Wg[g] + ((size_t)(d0 + i) * 512 + k0 + 4 * q));
                    ws2[g][2 * q + 0][i] = pack2h(v.x, v.y);
                    ws2[g][2 * q + 1][i] = pack2h(v.z, v.w);
                }
        }
        __syncthreads();
        #pragma unroll 2
        for (int p = 0; p < 16; ++p) {
            u32 x2[2][8];
            #pragma unroll
            for (int tt = 0; tt < 2; ++tt) {
                const uint4* xr = (const uint4*)&xs2[tt][p][bq * 8];
                uint4 xa = xr[0], xb = xr[1];
                x2[tt][0] = xa.x; x2[tt][1] = xa.y; x2[tt][2] = xa.z; x2[tt][3] = xa.w;
                x2[tt][4] = xb.x; x2[tt][5] = xb.y; x2[tt][6] = xb.z; x2[tt][7] = xb.w;
            }
            u32 w2[3][2];
            #pragma unroll
            for (int g = 0; g < 3; ++g) {
                w2[g][0] = ws2[g][p][d_l];
                w2[g][1] = ws2[g][p][d_l + 64];
            }
            #pragma unroll
            for (int tt = 0; tt < 2; ++tt)
                #pragma unroll
                for (int db = 0; db < 2; ++db)
                    #pragma unroll
                    for (int j = 0; j < 8; ++j)
                        #pragma unroll
                        for (int g = 0; g < 3; ++g)
                            acc[tt][db][j][g] = fdot2(x2[tt][j], w2[g][db], acc[tt][db][j][g]);
        }
        __syncthreads();
    }

    #pragma unroll
    for (int db = 0; db < 2; ++db) {
        const int d = d0 + 64 * db + d_l;
        const float b0 = 2.0f * bi[d];
        const float b1 = bz[d] + bi[d];
        const float b2 = bo[d] + bi[d];
        #pragma unroll
        for (int tt = 0; tt < 2; ++tt)
            #pragma unroll
            for (int j = 0; j < 8; ++j) {
                const size_t o = ((size_t)(t0 + tt) * 32 + (bq * 8 + j)) * 512 + d;
                Xi[o] = f2h(acc[tt][db][j][0] + b0);
                Xz[o] = f2h(acc[tt][db][j][1] + b1);
                Xo[o] = f2h(acc[tt][db][j][2] + b2);
            }
    }
}

// ---------------------------------------------------------------------------
// K2: sequential recurrence. One WG of 256 threads per batch element
// (1 wave/SIMD -> ~512-reg budget, NO spill). Thread (dg=tid>>2, kq=tid&3)
// computes 8 outputs d=8dg+j over K-quarter kq (64 pairs each):
//   - 13 uint4/output in VGPRs (416 regs)
//   - 15 uint4/thread in LDS (61 KB, sequential = conflict-free)
//   - 9 uint4/thread/step streamed from L2-hot WpkT (constant addresses)
// h stored in 288B-stride quarters so the 4 kq broadcast groups hit disjoint
// banks. DPP xor1+xor2 butterfly gives every lane all 8 sums; lane kq
// finalizes outputs 2kq,2kq+1 and writes one packed u32.
// ---------------------------------------------------------------------------
__global__ __launch_bounds__(256, 1) void k2_recur(
    const u16* __restrict__ Xi, const u16* __restrict__ Xz, const u16* __restrict__ Xo,
    const u32* __restrict__ WpkT, const u32* __restrict__ Wypk,
    const float* __restrict__ by, float* __restrict__ out)
{
    __shared__ alignas(16) uint4 wldsv[15 * 256];   // 61440 B
    __shared__ alignas(16) u16 hbuf[2][4 * 144];    // quarters @288B stride, 2304 B

    const int b   = blockIdx.x;
    const int tid = threadIdx.x;
    const int kq  = tid & 3;
    const int dg  = tid >> 2;

    const uint4* WpkT4 = (const uint4*)WpkT;        // row d = 64 uint4

    // -------- weight residency --------
    uint4 wv[8][13];
    #pragma unroll
    for (int j = 0; j < 8; ++j) {
        const uint4* rv = WpkT4 + (size_t)(8 * dg + j) * 64 + 16 * kq;
        #pragma unroll
        for (int i = 0; i < 13; ++i) wv[j][i] = rv[i];
        if (j < 7) {
            wldsv[(2 * j + 0) * 256 + tid] = rv[13];
            wldsv[(2 * j + 1) * 256 + tid] = rv[14];
        } else {
            wldsv[14 * 256 + tid] = rv[13];
        }
    }

    const int d0 = 8 * dg + 2 * kq;                 // first of this thread's 2 final outputs
    const int hq_ = d0 >> 7, hj_ = d0 & 127;
    u32* hw0 = (u32*)((char*)&hbuf[0][0] + hq_ * 288 + 2 * hj_);
    u32* hw1 = (u32*)((char*)&hbuf[1][0] + hq_ * 288 + 2 * hj_);
    *hw0 = 0u;                                      // h = 0 at t=0
    __syncthreads();

    const uint4* hv0 = (const uint4*)((const char*)&hbuf[0][0] + kq * 288);
    const uint4* hv1 = (const uint4*)((const char*)&hbuf[1][0] + kq * 288);

    // prefetch X for t=0 (two adjacent outputs -> one u32 per gate array)
    u32 xi_c = *(const u32*)(Xi + (size_t)b * 512 + d0);
    u32 xz_c = *(const u32*)(Xz + (size_t)b * 512 + d0);
    u32 xo_c = *(const u32*)(Xo + (size_t)b * 512 + d0);

    for (int t = 0; t < 2048; ++t) {
        const int cur = t & 1;
        const int tn = (t + 1) & 2047;
        const size_t xbase = ((size_t)tn * 32 + b) * 512 + d0;
        const u32 xi_n = *(const u32*)(Xi + xbase);
        const u32 xz_n = *(const u32*)(Xz + xbase);
        const u32 xo_n = *(const u32*)(Xo + xbase);

        const uint4* hv = cur ? hv1 : hv0;
        float a0 = 0.f, a1 = 0.f, a2 = 0.f, a3 = 0.f;
        float a4 = 0.f, a5 = 0.f, a6 = 0.f, a7 = 0.f;

        // i = 0..7 : VGPR weights
        #pragma unroll
        for (int i = 0; i < 8; ++i) {
            uint4 hc = hv[i];
            a0 = fdot2(hc.x, wv[0][i].x, a0); a0 = fdot2(hc.y, wv[0][i].y, a0);
            a0 = fdot2(hc.z, wv[0][i].z, a0); a0 = fdot2(hc.w, wv[0][i].w, a0);
            a1 = fdot2(hc.x, wv[1][i].x, a1); a1 = fdot2(hc.y, wv[1][i].y, a1);
            a1 = fdot2(hc.z, wv[1][i].z, a1); a1 = fdot2(hc.w, wv[1][i].w, a1);
            a2 = fdot2(hc.x, wv[2][i].x, a2); a2 = fdot2(hc.y, wv[2][i].y, a2);
            a2 = fdot2(hc.z, wv[2][i].z, a2); a2 = fdot2(hc.w, wv[2][i].w, a2);
            a3 = fdot2(hc.x, wv[3][i].x, a3); a3 = fdot2(hc.y, wv[3][i].y, a3);
            a3 = fdot2(hc.z, wv[3][i].z, a3); a3 = fdot2(hc.w, wv[3][i].w, a3);
            a4 = fdot2(hc.x, wv[4][i].x, a4); a4 = fdot2(hc.y, wv[4][i].y, a4);
            a4 = fdot2(hc.z, wv[4][i].z, a4); a4 = fdot2(hc.w, wv[4][i].w, a4);
            a5 = fdot2(hc.x, wv[5][i].x, a5); a5 = fdot2(hc.y, wv[5][i].y, a5);
            a5 = fdot2(hc.z, wv[5][i].z, a5); a5 = fdot2(hc.w, wv[5][i].w, a5);
            a6 = fdot2(hc.x, wv[6][i].x, a6); a6 = fdot2(hc.y, wv[6][i].y, a6);
            a6 = fdot2(hc.z, wv[6][i].z, a6); a6 = fdot2(hc.w, wv[6][i].w, a6);
            a7 = fdot2(hc.x, wv[7][i].x, a7); a7 = fdot2(hc.y, wv[7][i].y, a7);
            a7 = fdot2(hc.z, wv[7][i].z, a7); a7 = fdot2(hc.w, wv[7][i].w, a7);
        }

        // issue the L2-streamed tail weights now (consumed at i=14/15)
        uint4 g0 = WpkT4[(size_t)(8 * dg + 0) * 64 + 16 * kq + 15];
        uint4 g1 = WpkT4[(size_t)(8 * dg + 1) * 64 + 16 * kq + 15];
        uint4 g2 = WpkT4[(size_t)(8 * dg + 2) * 64 + 16 * kq + 15];
        uint4 g3 = WpkT4[(size_t)(8 * dg + 3) * 64 + 16 * kq + 15];
        uint4 g4 = WpkT4[(size_t)(8 * dg + 4) * 64 + 16 * kq + 15];
        uint4 g5 = WpkT4[(size_t)(8 * dg + 5) * 64 + 16 * kq + 15];
        uint4 g6 = WpkT4[(size_t)(8 * dg + 6) * 64 + 16 * kq + 15];
        uint4 g7a = WpkT4[(size_t)(8 * dg + 7) * 64 + 16 * kq + 14];
        uint4 g7b = WpkT4[(size_t)(8 * dg + 7) * 64 + 16 * kq + 15];

        // i = 8..12 : VGPR weights
        #pragma unroll
        for (int i = 8; i < 13; ++i) {
            uint4 hc = hv[i];
            a0 = fdot2(hc.x, wv[0][i].x, a0); a0 = fdot2(hc.y, wv[0][i].y, a0);
            a0 = fdot2(hc.z, wv[0][i].z, a0); a0 = fdot2(hc.w, wv[0][i].w, a0);
            a1 = fdot2(hc.x, wv[1][i].x, a1); a1 = fdot2(hc.y, wv[1][i].y, a1);
            a1 = fdot2(hc.z, wv[1][i].z, a1); a1 = fdot2(hc.w, wv[1][i].w, a1);
            a2 = fdot2(hc.x, wv[2][i].x, a2); a2 = fdot2(hc.y, wv[2][i].y, a2);
            a2 = fdot2(hc.z, wv[2][i].z, a2); a2 = fdot2(hc.w, wv[2][i].w, a2);
            a3 = fdot2(hc.x, wv[3][i].x, a3); a3 = fdot2(hc.y, wv[3][i].y, a3);
            a3 = fdot2(hc.z, wv[3][i].z, a3); a3 = fdot2(hc.w, wv[3][i].w, a3);
            a4 = fdot2(hc.x, wv[4][i].x, a4); a4 = fdot2(hc.y, wv[4][i].y, a4);
            a4 = fdot2(hc.z, wv[4][i].z, a4); a4 = fdot2(hc.w, wv[4][i].w, a4);
            a5 = fdot2(hc.x, wv[5][i].x, a5); a5 = fdot2(hc.y, wv[5][i].y, a5);
            a5 = fdot2(hc.z, wv[5][i].z, a5); a5 = fdot2(hc.w, wv[5][i].w, a5);
            a6 = fdot2(hc.x, wv[6][i].x, a6); a6 = fdot2(hc.y, wv[6][i].y, a6);
            a6 = fdot2(hc.z, wv[6][i].z, a6); a6 = fdot2(hc.w, wv[6][i].w, a6);
            a7 = fdot2(hc.x, wv[7][i].x, a7); a7 = fdot2(hc.y, wv[7][i].y, a7);
            a7 = fdot2(hc.z, wv[7][i].z, a7); a7 = fdot2(hc.w, wv[7][i].w, a7);
        }

        // i = 13 : LDS for all 8 outputs
        {
            uint4 hc = hv[13];
            uint4 l0 = wldsv[0 * 256 + tid];
            uint4 l1 = wldsv[2 * 256 + tid];
            uint4 l2 = wldsv[4 * 256 + tid];
            uint4 l3 = wldsv[6 * 256 + tid];
            uint4 l4 = wldsv[8 * 256 + tid];
            uint4 l5 = wldsv[10 * 256 + tid];
            uint4 l6 = wldsv[12 * 256 + tid];
            uint4 l7 = wldsv[14 * 256 + tid];
            a0 = fdot2(hc.x, l0.x, a0); a0 = fdot2(hc.y, l0.y, a0);
            a0 = fdot2(hc.z, l0.z, a0); a0 = fdot2(hc.w, l0.w, a0);
            a1 = fdot2(hc.x, l1.x, a1); a1 = fdot2(hc.y, l1.y, a1);
            a1 = fdot2(hc.z, l1.z, a1); a1 = fdot2(hc.w, l1.w, a1);
            a2 = fdot2(hc.x, l2.x, a2); a2 = fdot2(hc.y, l2.y, a2);
            a2 = fdot2(hc.z, l2.z, a2); a2 = fdot2(hc.w, l2.w, a2);
            a3 = fdot2(hc.x, l3.x, a3); a3 = fdot2(hc.y, l3.y, a3);
            a3 = fdot2(hc.z, l3.z, a3); a3 = fdot2(hc.w, l3.w, a3);
            a4 = fdot2(hc.x, l4.x, a4); a4 = fdot2(hc.y, l4.y, a4);
            a4 = fdot2(hc.z, l4.z, a4); a4 = fdot2(hc.w, l4.w, a4);
            a5 = fdot2(hc.x, l5.x, a5); a5 = fdot2(hc.y, l5.y, a5);
            a5 = fdot2(hc.z, l5.z, a5); a5 = fdot2(hc.w, l5.w, a5);
            a6 = fdot2(hc.x, l6.x, a6); a6 = fdot2(hc.y, l6.y, a6);
            a6 = fdot2(hc.z, l6.z, a6); a6 = fdot2(hc.w, l6.w, a6);
            a7 = fdot2(hc.x, l7.x, a7); a7 = fdot2(hc.y, l7.y, a7);
            a7 = fdot2(hc.z, l7.z, a7); a7 = fdot2(hc.w, l7.w, a7);
        }
        // i = 14 : j<7 LDS, j=7 global
        {
            uint4 hc = hv[14];
            uint4 l0 = wldsv[1 * 256 + tid];
            uint4 l1 = wldsv[3 * 256 + tid];
            uint4 l2 = wldsv[5 * 256 + tid];
            uint4 l3 = wldsv[7 * 256 + tid];
            uint4 l4 = wldsv[9 * 256 + tid];
            uint4 l5 = wldsv[11 * 256 + tid];
            uint4 l6 = wldsv[13 * 256 + tid];
            a0 = fdot2(hc.x, l0.x, a0); a0 = fdot2(hc.y, l0.y, a0);
            a0 = fdot2(hc.z, l0.z, a0); a0 = fdot2(hc.w, l0.w, a0);
            a1 = fdot2(hc.x, l1.x, a1); a1 = fdot2(hc.y, l1.y, a1);
            a1 = fdot2(hc.z, l1.z, a1); a1 = fdot2(hc.w, l1.w, a1);
            a2 = fdot2(hc.x, l2.x, a2); a2 = fdot2(hc.y, l2.y, a2);
            a2 = fdot2(hc.z, l2.z, a2); a2 = fdot2(hc.w, l2.w, a2);
            a3 = fdot2(hc.x, l3.x, a3); a3 = fdot2(hc.y, l3.y, a3);
            a3 = fdot2(hc.z, l3.z, a3); a3 = fdot2(hc.w, l3.w, a3);
            a4 = fdot2(hc.x, l4.x, a4); a4 = fdot2(hc.y, l4.y, a4);
            a4 = fdot2(hc.z, l4.z, a4); a4 = fdot2(hc.w, l4.w, a4);
            a5 = fdot2(hc.x, l5.x, a5); a5 = fdot2(hc.y, l5.y, a5);
            a5 = fdot2(hc.z, l5.z, a5); a5 = fdot2(hc.w, l5.w, a5);
            a6 = fdot2(hc.x, l6.x, a6); a6 = fdot2(hc.y, l6.y, a6);
            a6 = fdot2(hc.z, l6.z, a6); a6 = fdot2(hc.w, l6.w, a6);
            a7 = fdot2(hc.x, g7a.x, a7); a7 = fdot2(hc.y, g7a.y, a7);
            a7 = fdot2(hc.z, g7a.z, a7); a7 = fdot2(hc.w, g7a.w, a7);
        }
        // i = 15 : all global
        {
            uint4 hc = hv[15];
            a0 = fdot2(hc.x, g0.x, a0); a0 = fdot2(hc.y, g0.y, a0);
            a0 = fdot2(hc.z, g0.z, a0); a0 = fdot2(hc.w, g0.w, a0);
            a1 = fdot2(hc.x, g1.x, a1); a1 = fdot2(hc.y, g1.y, a1);
            a1 = fdot2(hc.z, g1.z, a1); a1 = fdot2(hc.w, g1.w, a1);
            a2 = fdot2(hc.x, g2.x, a2); a2 = fdot2(hc.y, g2.y, a2);
            a2 = fdot2(hc.z, g2.z, a2); a2 = fdot2(hc.w, g2.w, a2);
            a3 = fdot2(hc.x, g3.x, a3); a3 = fdot2(hc.y, g3.y, a3);
            a3 = fdot2(hc.z, g3.z, a3); a3 = fdot2(hc.w, g3.w, a3);
            a4 = fdot2(hc.x, g4.x, a4); a4 = fdot2(hc.y, g4.y, a4);
            a4 = fdot2(hc.z, g4.z, a4); a4 = fdot2(hc.w, g4.w, a4);
            a5 = fdot2(hc.x, g5.x, a5); a5 = fdot2(hc.y, g5.y, a5);
            a5 = fdot2(hc.z, g5.z, a5); a5 = fdot2(hc.w, g5.w, a5);
            a6 = fdot2(hc.x, g6.x, a6); a6 = fdot2(hc.y, g6.y, a6);
            a6 = fdot2(hc.z, g6.z, a6); a6 = fdot2(hc.w, g6.w, a6);
            a7 = fdot2(hc.x, g7b.x, a7); a7 = fdot2(hc.y, g7b.y, a7);
            a7 = fdot2(hc.z, g7b.z, a7); a7 = fdot2(hc.w, g7b.w, a7);
        }

        // butterfly over the quad (kq): every lane gets all 8 full sums
        a0 = dpp_xor_add<0xB1>(a0); a1 = dpp_xor_add<0xB1>(a1);
        a2 = dpp_xor_add<0xB1>(a2); a3 = dpp_xor_add<0xB1>(a3);
        a4 = dpp_xor_add<0xB1>(a4); a5 = dpp_xor_add<0xB1>(a5);
        a6 = dpp_xor_add<0xB1>(a6); a7 = dpp_xor_add<0xB1>(a7);
        a0 = dpp_xor_add<0x4E>(a0); a1 = dpp_xor_add<0x4E>(a1);
        a2 = dpp_xor_add<0x4E>(a2); a3 = dpp_xor_add<0x4E>(a3);
        a4 = dpp_xor_add<0x4E>(a4); a5 = dpp_xor_add<0x4E>(a5);
        a6 = dpp_xor_add<0x4E>(a6); a7 = dpp_xor_add<0x4E>(a7);

        // lane kq finalizes outputs d0=8dg+2kq and d0+1
        const float v0 = (kq & 2) ? ((kq & 1) ? a6 : a4) : ((kq & 1) ? a2 : a0);
        const float v1 = (kq & 2) ? ((kq & 1) ? a7 : a5) : ((kq & 1) ? a3 : a1);

        const f16x2 xi2 = __builtin_bit_cast(f16x2, xi_c);
        const f16x2 xz2 = __builtin_bit_cast(f16x2, xz_c);
        const f16x2 xo2 = __builtin_bit_cast(f16x2, xo_c);

        const float zi0 = fsigmoid((float)xi2[0] + v0);
        const float z0  = fsigmoid((float)xz2[0] + v0);
        const float zo0 = fsigmoid((float)xo2[0] + v0);
        const float hn0 = zo0 * ftanh_pos(zi0 * z0);
        const float zi1 = fsigmoid((float)xi2[1] + v1);
        const float z1  = fsigmoid((float)xz2[1] + v1);
        const float zo1 = fsigmoid((float)xo2[1] + v1);
        const float hn1 = zo1 * ftanh_pos(zi1 * z1);

        const u32 hwv = (u32)f2h(hn0) | ((u32)f2h(hn1) << 16);
        *(cur ? hw0 : hw1) = hwv;
        __syncthreads();

        xi_c = xi_n; xz_c = xz_n; xo_c = xo_n;
    }

    // epilogue: final h in hbuf[0]; out[b, d] = h @ Wy.T + by for d=tid, tid+256
    {
        float e0 = 0.f, e1 = 0.f;
        #pragma unroll
        for (int q = 0; q < 4; ++q) {
            const uint4* hq = (const uint4*)((const char*)&hbuf[0][0] + q * 288);
            #pragma unroll
            for (int i = 0; i < 16; ++i) {
                uint4 hc = hq[i];
                const int p = 64 * q + 4 * i;
                e0 = fdot2(hc.x, Wypk[(size_t)(p + 0) * 512 + tid], e0);
                e0 = fdot2(hc.y, Wypk[(size_t)(p + 1) * 512 + tid], e0);
                e0 = fdot2(hc.z, Wypk[(size_t)(p + 2) * 512 + tid], e0);
                e0 = fdot2(hc.w, Wypk[(size_t)(p + 3) * 512 + tid], e0);
                e1 = fdot2(hc.x, Wypk[(size_t)(p + 0) * 512 + tid + 256], e1);
                e1 = fdot2(hc.y, Wypk[(size_t)(p + 1) * 512 + tid + 256], e1);
                e1 = fdot2(hc.z, Wypk[(size_t)(p + 2) * 512 + tid + 256], e1);
                e1 = fdot2(hc.w, Wypk[(size_t)(p + 3) * 512 + tid + 256], e1);
            }
        }
        out[(size_t)b * 512 + tid]       = e0 + by[tid];
        out[(size_t)b * 512 + tid + 256] = e1 + by[tid + 256];
    }
}

// ---------------------------------------------------------------------------
extern "C" void kernel_launch(void* const* d_in, const int* in_sizes, int n_in,
                              void* d_out, int out_size, void* d_ws, size_t ws_size,
                              hipStream_t stream) {
    const float* word = (const float*)d_in[0];
    // d_in[1]=Wf, d_in[2]=bf : dead in the reference (c==0 path), unused.
    const float* Wi = (const float*)d_in[3];
    const float* bi = (const float*)d_in[4];
    const float* Wz = (const float*)d_in[5];
    const float* bz = (const float*)d_in[6];
    const float* Wo = (const float*)d_in[7];
    const float* bo = (const float*)d_in[8];
    const float* Wy = (const float*)d_in[9];
    const float* by = (const float*)d_in[10];
    float* out = (float*)d_out;

    char* ws = (char*)d_ws;
    const size_t XN = (size_t)2048 * 32 * 512 * sizeof(u16);  // 64 MB per gate array
    u16* Xi = (u16*)(ws);
    u16* Xz = (u16*)(ws + XN);
    u16* Xo = (u16*)(ws + 2 * XN);
    u32* WpkT = (u32*)(ws + 3 * XN);                  // 512 KB
    u32* Wypk = (u32*)(ws + 3 * XN + (size_t)524288); // 512 KB

    k0_pack<<<768, 256, 0, stream>>>(Wi, Wy, WpkT, Wypk);

    dim3 g1(1024, 4);
    k1_gates<<<g1, 256, 0, stream>>>(word, Wi, Wz, Wo, bi, bz, bo, Xi, Xz, Xo);

    k2_recur<<<32, 256, 0, stream>>>(Xi, Xz, Xo, WpkT, Wypk, by, out);
}

// Round 4
// 5574.434 us; speedup vs baseline: 1.1148x; 1.1148x over previous
//
#include <hip/hip_runtime.h>

typedef unsigned int u32;
typedef unsigned short u16;
typedef _Float16 f16;
typedef f16 f16x2 __attribute__((ext_vector_type(2)));

__device__ __forceinline__ float fdot2(u32 a, u32 b, float c) {
#if __has_builtin(__builtin_amdgcn_fdot2)
    return __builtin_amdgcn_fdot2(__builtin_bit_cast(f16x2, a),
                                  __builtin_bit_cast(f16x2, b), c, false);
#else
    f16x2 av = __builtin_bit_cast(f16x2, a), bv = __builtin_bit_cast(f16x2, b);
    c += (float)av[0] * (float)bv[0];
    c += (float)av[1] * (float)bv[1];
    return c;
#endif
}

__device__ __forceinline__ u32 pack2h(float a, float b) {
    f16x2 h; h[0] = (f16)a; h[1] = (f16)b;
    return __builtin_bit_cast(u32, h);
}
__device__ __forceinline__ float h2f(u16 x) { return (float)__builtin_bit_cast(f16, x); }
__device__ __forceinline__ u16 f2h(float x) { f16 h = (f16)x; return __builtin_bit_cast(u16, h); }

__device__ __forceinline__ float fexp(float x) {
#if __has_builtin(__builtin_amdgcn_exp2f)
    return __builtin_amdgcn_exp2f(x * 1.44269504088896f);
#else
    return __expf(x);
#endif
}
__device__ __forceinline__ float frcp(float x) {
#if __has_builtin(__builtin_amdgcn_rcpf)
    return __builtin_amdgcn_rcpf(x);
#else
    return 1.0f / x;
#endif
}
__device__ __forceinline__ float fsigmoid(float x) { return frcp(1.0f + fexp(-x)); }
__device__ __forceinline__ float ftanh_pos(float x) { return 1.0f - 2.0f * frcp(fexp(2.0f * x) + 1.0f); }

template <int CTRL>
__device__ __forceinline__ float dpp_xor_add(float x) {
    int y = __builtin_amdgcn_update_dpp(0, __builtin_bit_cast(int, x), CTRL, 0xF, 0xF, true);
    return x + __builtin_bit_cast(float, y);
}

// ---------------------------------------------------------------------------
// K0: pack weights.
//   WpkT[d][p] = (Wi[d][2p], Wi[d][2p+1])   d<512, p<256
//   Wypk[p][d] = (Wy[d][2p], Wy[d][2p+1])
//   Wstr[t*12 + j] : per-k2-thread streamed tail pairs (see k2 residency map)
// ---------------------------------------------------------------------------
__global__ __launch_bounds__(256) void k0_pack(const float* __restrict__ Wi,
                                               const float* __restrict__ Wy,
                                               u32* __restrict__ WpkT,
                                               u32* __restrict__ Wypk,
                                               u32* __restrict__ Wstr) {
    const int bx = blockIdx.x, tid = threadIdx.x;
    if (bx < 512) {
        const float2 v = *(const float2*)(Wi + (size_t)bx * 512 + 2 * tid);
        WpkT[(size_t)bx * 256 + tid] = pack2h(v.x, v.y);
    } else if (bx < 768) {
        const int p = bx - 512;
        #pragma unroll
        for (int r = 0; r < 2; ++r) {
            const int d = tid + 256 * r;
            Wypk[(size_t)p * 512 + d] =
                pack2h(Wy[(size_t)d * 512 + 2 * p], Wy[(size_t)d * 512 + 2 * p + 1]);
        }
    } else {
        // streamed tail pairs for k2 thread t = tid
        const int dg = tid >> 2, kq = tid & 3;
        #pragma unroll
        for (int j = 0; j < 7; ++j) {            // rows 0..6: pair p_local=63
            const int d = 8 * dg + j, p = 64 * kq + 63;
            Wstr[tid * 12 + j] = pack2h(Wi[(size_t)d * 512 + 2 * p],
                                        Wi[(size_t)d * 512 + 2 * p + 1]);
        }
        #pragma unroll
        for (int m = 0; m < 5; ++m) {            // row 7: pairs p_local=59..63
            const int d = 8 * dg + 7, p = 64 * kq + 59 + m;
            Wstr[tid * 12 + 7 + m] = pack2h(Wi[(size_t)d * 512 + 2 * p],
                                            Wi[(size_t)d * 512 + 2 * p + 1]);
        }
    }
}

// ---------------------------------------------------------------------------
// K1: gate pre-activations. W tile transposed to uint4 cells (b128 reads),
// XOR-swizzled column to keep LDS banks even. 29.2 KB LDS -> 2 WGs/CU.
// ---------------------------------------------------------------------------
__global__ __launch_bounds__(256) void k1_gates(
    const float* __restrict__ word,
    const float* __restrict__ Wi, const float* __restrict__ Wz, const float* __restrict__ Wo,
    const float* __restrict__ bi, const float* __restrict__ bz, const float* __restrict__ bo,
    u16* __restrict__ Xi, u16* __restrict__ Xz, u16* __restrict__ Xo)
{
    __shared__ uint4 ws2v[3][128][4];   // [gate][row][swizzled pg]  24576 B
    __shared__ u32 xs2[2][16][36];      // [t-sub][pair][b pad 36]    4608 B

    const int tid = threadIdx.x;
    const int d_l = tid & 63;
    const int bq  = tid >> 6;
    const int t0  = blockIdx.x * 2;
    const int d0  = blockIdx.y * 128;

    const float* Wg[3] = {Wi, Wz, Wo};

    float acc[2][2][8][3];
    #pragma unroll
    for (int tt = 0; tt < 2; ++tt)
        #pragma unroll
        for (int db = 0; db < 2; ++db)
            #pragma unroll
            for (int j = 0; j < 8; ++j)
                #pragma unroll
                for (int g = 0; g < 3; ++g) acc[tt][db][j][g] = 0.0f;

    for (int k0c = 0; k0c < 512; k0c += 32) {
        // stage x: 2t x 16 pairs x 32b
        {
            const int p = tid & 15, bg = tid >> 4;
            #pragma unroll
            for (int tt = 0; tt < 2; ++tt)
                #pragma unroll
                for (int j = 0; j < 2; ++j) {
                    const int bb = bg * 2 + j;
                    const float2 v = *(const float2*)(word + (((size_t)(t0 + tt) * 32 + bb) * 512 + k0c + 2 * p));
                    xs2[tt][p][bb] = pack2h(v.x, v.y);
                }
        }
        // stage W cells: 1536 cells, 6 per thread; cell (g,i,pg) = pairs 4pg..4pg+3 of row i
        {
            #pragma unroll
            for (int cc = 0; cc < 6; ++cc) {
                const int c = tid + 256 * cc;
                const int g = c >> 9, r = c & 511, pg = r >> 7, i = r & 127;
                const float* src = Wg[g] + (size_t)(d0 + i) * 512 + k0c + 8 * pg;
                const float4 v0 = ((const float4*)src)[0];
                const float4 v1 = ((const float4*)src)[1];
                uint4 cell;
                cell.x = pack2h(v0.x, v0.y); cell.y = pack2h(v0.z, v0.w);
                cell.z = pack2h(v1.x, v1.y); cell.w = pack2h(v1.z, v1.w);
                ws2v[g][i][(pg + (i >> 2)) & 3] = cell;
            }
        }
        __syncthreads();
        #pragma unroll
        for (int pg = 0; pg < 4; ++pg) {
            uint4 wc[3][2];
            #pragma unroll
            for (int g = 0; g < 3; ++g)
                #pragma unroll
                for (int db = 0; db < 2; ++db) {
                    const int d = d_l + 64 * db;
                    wc[g][db] = ws2v[g][d][(pg + (d >> 2)) & 3];
                }
            #pragma unroll
            for (int p = 0; p < 4; ++p) {
                const int pair = 4 * pg + p;
                u32 x2[2][8];
                #pragma unroll
                for (int tt = 0; tt < 2; ++tt) {
                    const uint4* xr = (const uint4*)&xs2[tt][pair][bq * 8];
                    uint4 xa = xr[0], xb = xr[1];
                    x2[tt][0] = xa.x; x2[tt][1] = xa.y; x2[tt][2] = xa.z; x2[tt][3] = xa.w;
                    x2[tt][4] = xb.x; x2[tt][5] = xb.y; x2[tt][6] = xb.z; x2[tt][7] = xb.w;
                }
                u32 w[3][2];
                #pragma unroll
                for (int g = 0; g < 3; ++g)
                    #pragma unroll
                    for (int db = 0; db < 2; ++db) {
                        const uint4 v = wc[g][db];
                        w[g][db] = (p == 0) ? v.x : (p == 1) ? v.y : (p == 2) ? v.z : v.w;
                    }
                #pragma unroll
                for (int tt = 0; tt < 2; ++tt)
                    #pragma unroll
                    for (int db = 0; db < 2; ++db)
                        #pragma unroll
                        for (int j = 0; j < 8; ++j)
                            #pragma unroll
                            for (int g = 0; g < 3; ++g)
                                acc[tt][db][j][g] = fdot2(x2[tt][j], w[g][db], acc[tt][db][j][g]);
            }
        }
        __syncthreads();
    }

    #pragma unroll
    for (int db = 0; db < 2; ++db) {
        const int d = d0 + 64 * db + d_l;
        const float b0 = 2.0f * bi[d];
        const float b1 = bz[d] + bi[d];
        const float b2 = bo[d] + bi[d];
        #pragma unroll
        for (int tt = 0; tt < 2; ++tt)
            #pragma unroll
            for (int j = 0; j < 8; ++j) {
                const size_t o = ((size_t)(t0 + tt) * 32 + (bq * 8 + j)) * 512 + d;
                Xi[o] = f2h(acc[tt][db][j][0] + b0);
                Xz[o] = f2h(acc[tt][db][j][1] + b1);
                Xo[o] = f2h(acc[tt][db][j][2] + b2);
            }
    }
}

// ---------------------------------------------------------------------------
// K2 residency map (thread = (dg=tid>>2, kq=tid&3); 8 rows x 64 pairs = 512 u32):
//   rows 0..7:  p 0..22  -> arch VGPR wv[j][0..22]           (184 regs)
//               p 23..54 -> AGPR ag{j}_{0..31} via inline asm (256 AGPRs)
//   rows 0..6:  p 55..62 -> LDS cells 2j,2j+1 ; p 63 -> Wstr stream
//   row  7:     p 55..58 -> LDS cell 14      ; p 59..63 -> Wstr stream
// h in 288B-stride quarters; DPP quad butterfly; one barrier/step.
// ---------------------------------------------------------------------------
#define FOR8(M) M(0) M(1) M(2) M(3) M(4) M(5) M(6) M(7)
#define FOR7(M) M(0) M(1) M(2) M(3) M(4) M(5) M(6)
#define FOR8I(M, i) M(0,i) M(1,i) M(2,i) M(3,i) M(4,i) M(5,i) M(6,i) M(7,i)
#define FOR8I4(M, a,b,c,d) M(0,a,b,c,d) M(1,a,b,c,d) M(2,a,b,c,d) M(3,a,b,c,d) M(4,a,b,c,d) M(5,a,b,c,d) M(6,a,b,c,d) M(7,a,b,c,d)

#define AGLIST(M, j) M(j,0) M(j,1) M(j,2) M(j,3) M(j,4) M(j,5) M(j,6) M(j,7) \
    M(j,8) M(j,9) M(j,10) M(j,11) M(j,12) M(j,13) M(j,14) M(j,15) M(j,16) M(j,17) \
    M(j,18) M(j,19) M(j,20) M(j,21) M(j,22) M(j,23) M(j,24) M(j,25) M(j,26) M(j,27) \
    M(j,28) M(j,29) M(j,30) M(j,31)
#define AG_DECL1(j,i) u32 ag##j##_##i;
#define AG_DECL_ROW(j) AGLIST(AG_DECL1, j)

#define AGW(j,i,v) asm volatile("v_accvgpr_write_b32 %0, %1" : "=a"(ag##j##_##i) : "v"(v));
#define AGR(d,j,i) asm volatile("v_accvgpr_read_b32 %0, %1" : "=v"(d) : "a"(ag##j##_##i));

#define ROW_INIT(j) { \
    const uint4* rv = WpkT4 + (size_t)(8*dg + (j))*64 + 16*kq; \
    uint4 r; \
    r = rv[5];  wv[j][20]=r.x; wv[j][21]=r.y; wv[j][22]=r.z; AGW(j,0,r.w) \
    r = rv[6];  AGW(j,1,r.x)  AGW(j,2,r.y)  AGW(j,3,r.z)  AGW(j,4,r.w) \
    r = rv[7];  AGW(j,5,r.x)  AGW(j,6,r.y)  AGW(j,7,r.z)  AGW(j,8,r.w) \
    r = rv[8];  AGW(j,9,r.x)  AGW(j,10,r.y) AGW(j,11,r.z) AGW(j,12,r.w) \
    r = rv[9];  AGW(j,13,r.x) AGW(j,14,r.y) AGW(j,15,r.z) AGW(j,16,r.w) \
    r = rv[10]; AGW(j,17,r.x) AGW(j,18,r.y) AGW(j,19,r.z) AGW(j,20,r.w) \
    r = rv[11]; AGW(j,21,r.x) AGW(j,22,r.y) AGW(j,23,r.z) AGW(j,24,r.w) \
    r = rv[12]; AGW(j,25,r.x) AGW(j,26,r.y) AGW(j,27,r.z) AGW(j,28,r.w) \
    r = rv[13]; AGW(j,29,r.x) AGW(j,30,r.y) AGW(j,31,r.z) \
    const u32 p55 = r.w; \
    r = rv[14]; \
    { uint4 ca; ca.x = p55; ca.y = r.x; ca.z = r.y; ca.w = r.z; \
      if ((j) < 7) { const u32 p59 = r.w; r = rv[15]; \
            uint4 cb; cb.x = p59; cb.y = r.x; cb.z = r.y; cb.w = r.z; \
            wld4st[2*(j)] = ca; wld4st[2*(j)+1] = cb; } \
      else wld4st[14] = ca; } \
    r = rv[0]; wv[j][0]=r.x;  wv[j][1]=r.y;  wv[j][2]=r.z;  wv[j][3]=r.w; \
    r = rv[1]; wv[j][4]=r.x;  wv[j][5]=r.y;  wv[j][6]=r.z;  wv[j][7]=r.w; \
    r = rv[2]; wv[j][8]=r.x;  wv[j][9]=r.y;  wv[j][10]=r.z; wv[j][11]=r.w; \
    r = rv[3]; wv[j][12]=r.x; wv[j][13]=r.y; wv[j][14]=r.z; wv[j][15]=r.w; \
    r = rv[4]; wv[j][16]=r.x; wv[j][17]=r.y; wv[j][18]=r.z; wv[j][19]=r.w; \
}

#define ROW_A(j, i) \
    acc[j] = fdot2(hc.x, wv[j][4*(i)+0], acc[j]); \
    acc[j] = fdot2(hc.y, wv[j][4*(i)+1], acc[j]); \
    acc[j] = fdot2(hc.z, wv[j][4*(i)+2], acc[j]); \
    acc[j] = fdot2(hc.w, wv[j][4*(i)+3], acc[j]);

#define ROW_I5(j) { \
    acc[j] = fdot2(hc.x, wv[j][20], acc[j]); \
    acc[j] = fdot2(hc.y, wv[j][21], acc[j]); \
    acc[j] = fdot2(hc.z, wv[j][22], acc[j]); \
    u32 t; AGR(t, j, 0) acc[j] = fdot2(hc.w, t, acc[j]); }

#define ROW_G(j, i0,i1,i2,i3) { u32 t0,t1,t2,t3; \
    AGR(t0,j,i0) AGR(t1,j,i1) AGR(t2,j,i2) AGR(t3,j,i3) \
    acc[j] = fdot2(hc.x, t0, acc[j]); acc[j] = fdot2(hc.y, t1, acc[j]); \
    acc[j] = fdot2(hc.z, t2, acc[j]); acc[j] = fdot2(hc.w, t3, acc[j]); }

#define ROW_I13(j) { u32 t0,t1,t2; AGR(t0,j,29) AGR(t1,j,30) AGR(t2,j,31) \
    acc[j] = fdot2(hc13.x, t0, acc[j]); acc[j] = fdot2(hc13.y, t1, acc[j]); \
    acc[j] = fdot2(hc13.z, t2, acc[j]); }

#define ROW_TAIL(j) { const uint4 ca = wld4[2*(j)], cb = wld4[2*(j)+1]; \
    acc[j] = fdot2(hc13.w, ca.x, acc[j]); \
    acc[j] = fdot2(hc14.x, ca.y, acc[j]); acc[j] = fdot2(hc14.y, ca.z, acc[j]); \
    acc[j] = fdot2(hc14.z, ca.w, acc[j]); acc[j] = fdot2(hc14.w, cb.x, acc[j]); \
    acc[j] = fdot2(hc15.x, cb.y, acc[j]); acc[j] = fdot2(hc15.y, cb.z, acc[j]); \
    acc[j] = fdot2(hc15.z, cb.w, acc[j]); acc[j] = fdot2(hc15.w, sarr[j], acc[j]); }

__global__ __launch_bounds__(256, 1) void k2_recur(
    const u16* __restrict__ Xi, const u16* __restrict__ Xz, const u16* __restrict__ Xo,
    const u32* __restrict__ WpkT, const u32* __restrict__ Wypk,
    const u32* __restrict__ Wstr,
    const float* __restrict__ by, float* __restrict__ out)
{
    __shared__ alignas(16) uint4 wldsv[256 * 15];   // 61440 B
    __shared__ alignas(16) u16 hbuf[2][4 * 144];    // 288B-stride quarters, 2304 B

    const int b   = blockIdx.x;
    const int tid = threadIdx.x;
    const int kq  = tid & 3;
    const int dg  = tid >> 2;

    const uint4* WpkT4 = (const uint4*)WpkT;
    uint4* wld4st = wldsv + tid * 15;
    const uint4* wld4 = wldsv + tid * 15;

    u32 wv[8][23];
    FOR8(AG_DECL_ROW)
    FOR8(ROW_INIT)

    const int d0 = 8 * dg + 2 * kq;
    const int hq_ = d0 >> 7, hj_ = d0 & 127;
    u32* hw0 = (u32*)((char*)&hbuf[0][0] + hq_ * 288 + 2 * hj_);
    u32* hw1 = (u32*)((char*)&hbuf[1][0] + hq_ * 288 + 2 * hj_);
    *hw0 = 0u;
    __syncthreads();

    const uint4* hv0 = (const uint4*)((const char*)&hbuf[0][0] + kq * 288);
    const uint4* hv1 = (const uint4*)((const char*)&hbuf[1][0] + kq * 288);
    const uint4* Wstr4 = (const uint4*)(Wstr + tid * 12);

    u32 xi_c = *(const u32*)(Xi + (size_t)b * 512 + d0);
    u32 xz_c = *(const u32*)(Xz + (size_t)b * 512 + d0);
    u32 xo_c = *(const u32*)(Xo + (size_t)b * 512 + d0);

    for (int t = 0; t < 2048; ++t) {
        const int cur = t & 1;
        // issue L2-hot stream + next-X loads early; consumed at tail / next iter
        const uint4 sv0 = Wstr4[0], sv1 = Wstr4[1], sv2 = Wstr4[2];
        const int tn = (t + 1) & 2047;
        const size_t xbase = ((size_t)tn * 32 + b) * 512 + d0;
        const u32 xi_n = *(const u32*)(Xi + xbase);
        const u32 xz_n = *(const u32*)(Xz + xbase);
        const u32 xo_n = *(const u32*)(Xo + xbase);

        const uint4* hv = cur ? hv1 : hv0;
        float acc[8] = {0.f, 0.f, 0.f, 0.f, 0.f, 0.f, 0.f, 0.f};

        uint4 hc;
        hc = hv[0];  FOR8I(ROW_A, 0)
        hc = hv[1];  FOR8I(ROW_A, 1)
        hc = hv[2];  FOR8I(ROW_A, 2)
        hc = hv[3];  FOR8I(ROW_A, 3)
        hc = hv[4];  FOR8I(ROW_A, 4)
        hc = hv[5];  FOR8(ROW_I5)
        hc = hv[6];  FOR8I4(ROW_G, 1, 2, 3, 4)
        hc = hv[7];  FOR8I4(ROW_G, 5, 6, 7, 8)
        hc = hv[8];  FOR8I4(ROW_G, 9, 10, 11, 12)
        hc = hv[9];  FOR8I4(ROW_G, 13, 14, 15, 16)
        hc = hv[10]; FOR8I4(ROW_G, 17, 18, 19, 20)
        hc = hv[11]; FOR8I4(ROW_G, 21, 22, 23, 24)
        hc = hv[12]; FOR8I4(ROW_G, 25, 26, 27, 28)
        const uint4 hc13 = hv[13];
        FOR8(ROW_I13)
        const uint4 hc14 = hv[14], hc15 = hv[15];
        const u32 sarr[12] = {sv0.x, sv0.y, sv0.z, sv0.w,
                              sv1.x, sv1.y, sv1.z, sv1.w,
                              sv2.x, sv2.y, sv2.z, sv2.w};
        FOR7(ROW_TAIL)
        {   // row 7: LDS cell 14 + 5 streamed pairs
            const uint4 ca = wld4[14];
            acc[7] = fdot2(hc13.w, ca.x, acc[7]);
            acc[7] = fdot2(hc14.x, ca.y, acc[7]);
            acc[7] = fdot2(hc14.y, ca.z, acc[7]);
            acc[7] = fdot2(hc14.z, ca.w, acc[7]);
            acc[7] = fdot2(hc14.w, sarr[7], acc[7]);
            acc[7] = fdot2(hc15.x, sarr[8], acc[7]);
            acc[7] = fdot2(hc15.y, sarr[9], acc[7]);
            acc[7] = fdot2(hc15.z, sarr[10], acc[7]);
            acc[7] = fdot2(hc15.w, sarr[11], acc[7]);
        }

        // quad butterfly: every lane gets all 8 full sums
        #pragma unroll
        for (int j = 0; j < 8; ++j) acc[j] = dpp_xor_add<0xB1>(acc[j]);
        #pragma unroll
        for (int j = 0; j < 8; ++j) acc[j] = dpp_xor_add<0x4E>(acc[j]);

        const float v0 = (kq & 2) ? ((kq & 1) ? acc[6] : acc[4]) : ((kq & 1) ? acc[2] : acc[0]);
        const float v1 = (kq & 2) ? ((kq & 1) ? acc[7] : acc[5]) : ((kq & 1) ? acc[3] : acc[1]);

        const f16x2 xi2 = __builtin_bit_cast(f16x2, xi_c);
        const f16x2 xz2 = __builtin_bit_cast(f16x2, xz_c);
        const f16x2 xo2 = __builtin_bit_cast(f16x2, xo_c);

        const float zi0 = fsigmoid((float)xi2[0] + v0);
        const float z0  = fsigmoid((float)xz2[0] + v0);
        const float zo0 = fsigmoid((float)xo2[0] + v0);
        const float hn0 = zo0 * ftanh_pos(zi0 * z0);
        const float zi1 = fsigmoid((float)xi2[1] + v1);
        const float z1  = fsigmoid((float)xz2[1] + v1);
        const float zo1 = fsigmoid((float)xo2[1] + v1);
        const float hn1 = zo1 * ftanh_pos(zi1 * z1);

        const u32 hwv = (u32)f2h(hn0) | ((u32)f2h(hn1) << 16);
        *(cur ? hw0 : hw1) = hwv;
        __syncthreads();

        xi_c = xi_n; xz_c = xz_n; xo_c = xo_n;
    }

    // epilogue: final h in hbuf[0]; out[b, d] = h @ Wy.T + by for d=tid, tid+256
    {
        float e0 = 0.f, e1 = 0.f;
        #pragma unroll
        for (int q = 0; q < 4; ++q) {
            const uint4* hq = (const uint4*)((const char*)&hbuf[0][0] + q * 288);
            #pragma unroll
            for (int i = 0; i < 16; ++i) {
                uint4 hc = hq[i];
                const int p = 64 * q + 4 * i;
                e0 = fdot2(hc.x, Wypk[(size_t)(p + 0) * 512 + tid], e0);
                e0 = fdot2(hc.y, Wypk[(size_t)(p + 1) * 512 + tid], e0);
                e0 = fdot2(hc.z, Wypk[(size_t)(p + 2) * 512 + tid], e0);
                e0 = fdot2(hc.w, Wypk[(size_t)(p + 3) * 512 + tid], e0);
                e1 = fdot2(hc.x, Wypk[(size_t)(p + 0) * 512 + tid + 256], e1);
                e1 = fdot2(hc.y, Wypk[(size_t)(p + 1) * 512 + tid + 256], e1);
                e1 = fdot2(hc.z, Wypk[(size_t)(p + 2) * 512 + tid + 256], e1);
                e1 = fdot2(hc.w, Wypk[(size_t)(p + 3) * 512 + tid + 256], e1);
            }
        }
        out[(size_t)b * 512 + tid]       = e0 + by[tid];
        out[(size_t)b * 512 + tid + 256] = e1 + by[tid + 256];
    }
}

// ---------------------------------------------------------------------------
extern "C" void kernel_launch(void* const* d_in, const int* in_sizes, int n_in,
                              void* d_out, int out_size, void* d_ws, size_t ws_size,
                              hipStream_t stream) {
    const float* word = (const float*)d_in[0];
    // d_in[1]=Wf, d_in[2]=bf : dead in the reference (c==0 path), unused.
    const float* Wi = (const float*)d_in[3];
    const float* bi = (const float*)d_in[4];
    const float* Wz = (const float*)d_in[5];
    const float* bz = (const float*)d_in[6];
    const float* Wo = (const float*)d_in[7];
    const float* bo = (const float*)d_in[8];
    const float* Wy = (const float*)d_in[9];
    const float* by = (const float*)d_in[10];
    float* out = (float*)d_out;

    char* ws = (char*)d_ws;
    const size_t XN = (size_t)2048 * 32 * 512 * sizeof(u16);  // 64 MB per gate array
    u16* Xi = (u16*)(ws);
    u16* Xz = (u16*)(ws + XN);
    u16* Xo = (u16*)(ws + 2 * XN);
    u32* WpkT = (u32*)(ws + 3 * XN);                            // 256 KB
    u32* Wypk = (u32*)(ws + 3 * XN + (size_t)524288);           // 512 KB
    u32* Wstr = (u32*)(ws + 3 * XN + (size_t)2 * 524288);       // 12 KB

    k0_pack<<<769, 256, 0, stream>>>(Wi, Wy, WpkT, Wypk, Wstr);

    dim3 g1(1024, 4);
    k1_gates<<<g1, 256, 0, stream>>>(word, Wi, Wz, Wo, bi, bz, bo, Xi, Xz, Xo);

    k2_recur<<<32, 256, 0, stream>>>(Xi, Xz, Xo, WpkT, Wypk, Wstr, by, out);
}